// Round 1
// baseline (2919.556 us; speedup 1.0000x reference)
//
#include <hip/hip_runtime.h>
#include <cstdint>

#define H 3
#define C 64
#define HC 192
#define NEG 0.2f

#define N_A 10000
#define N_T 100000
#define N_U 50000
#define E0c 200000
#define E1c 300000
#define E2c 300000

// ---------------- float ordered-uint encode (for atomicMax on float) -------
__device__ __forceinline__ unsigned fenc(float f) {
  unsigned u = __float_as_uint(f);
  return (u >> 31) ? ~u : (u | 0x80000000u);
}
__device__ __forceinline__ float fdec(unsigned e) {
  return (e >> 31) ? __uint_as_float(e & 0x7FFFFFFFu) : __uint_as_float(~e);
}

// ---------------- GEMM: C[N,192] = A[N,K] @ W[K,192], fp32 -----------------
#define BM 128
#define BN 64
#define BK 16

__global__ __launch_bounds__(256) void gemm_f32(
    const float* __restrict__ A, const float* __restrict__ W,
    float* __restrict__ Cmat, int N, int K) {
  __shared__ float As[BK][BM + 4];
  __shared__ float Bs[BK][BN + 4];
  const int tid = threadIdx.x;
  const int bm = blockIdx.x * BM;
  const int bn = blockIdx.y * BN;
  const int tx = tid & 15, ty = tid >> 4;
  float acc[8][4];
#pragma unroll
  for (int i = 0; i < 8; ++i)
#pragma unroll
    for (int j = 0; j < 4; ++j) acc[i][j] = 0.f;

  for (int k0 = 0; k0 < K; k0 += BK) {
    // A tile 128x16 = 512 float4, 2 per thread
#pragma unroll
    for (int i = 0; i < 2; ++i) {
      int idx = tid + i * 256;
      int m = idx >> 2, k4 = idx & 3;
      int gm = bm + m;
      float4 v = make_float4(0.f, 0.f, 0.f, 0.f);
      if (gm < N) v = *(const float4*)(A + (size_t)gm * K + k0 + k4 * 4);
      As[k4 * 4 + 0][m] = v.x;
      As[k4 * 4 + 1][m] = v.y;
      As[k4 * 4 + 2][m] = v.z;
      As[k4 * 4 + 3][m] = v.w;
    }
    // B tile 16x64 = 256 float4, 1 per thread
    {
      int k = tid >> 4, n4 = tid & 15;
      float4 v = *(const float4*)(W + (size_t)(k0 + k) * HC + bn + n4 * 4);
      *(float4*)&Bs[k][n4 * 4] = v;
    }
    __syncthreads();
#pragma unroll
    for (int k = 0; k < BK; ++k) {
      float4 a0 = *(const float4*)&As[k][ty * 8];
      float4 a1 = *(const float4*)&As[k][ty * 8 + 4];
      float4 b = *(const float4*)&Bs[k][tx * 4];
      float av[8] = {a0.x, a0.y, a0.z, a0.w, a1.x, a1.y, a1.z, a1.w};
      float bv[4] = {b.x, b.y, b.z, b.w};
#pragma unroll
      for (int i = 0; i < 8; ++i)
#pragma unroll
        for (int j = 0; j < 4; ++j) acc[i][j] += av[i] * bv[j];
    }
    __syncthreads();
  }
#pragma unroll
  for (int i = 0; i < 8; ++i) {
    int gm = bm + ty * 8 + i;
    if (gm < N) {
      float4 v = make_float4(acc[i][0], acc[i][1], acc[i][2], acc[i][3]);
      *(float4*)(Cmat + (size_t)gm * HC + bn + tx * 4) = v;
    }
  }
}

// ------------- wv[k][h] = sum_c W[k][h*64+c] * a[h*64+c] -------------------
__global__ void wvec_kernel(const float* __restrict__ W,
                            const float* __restrict__ a,
                            float* __restrict__ wv, int K) {
  int k = blockIdx.x * blockDim.x + threadIdx.x;
  if (k >= K) return;
#pragma unroll
  for (int h = 0; h < H; ++h) {
    float s = 0.f;
    for (int c = 0; c < C; ++c) s += W[(size_t)k * HC + h * C + c] * a[h * C + c];
    wv[k * H + h] = s;
  }
}

// ------------- out[n][h] = sum_k x[n][k] * wv[k][h]  (wave per node) -------
__global__ void attn_proj(const float* __restrict__ x,
                          const float* __restrict__ wv,
                          float* __restrict__ out, int N, int K) {
  int lane = threadIdx.x & 63;
  int node = (blockIdx.x * blockDim.x + threadIdx.x) >> 6;
  if (node >= N) return;
  float p0 = 0.f, p1 = 0.f, p2 = 0.f;
  for (int k = lane; k < K; k += 64) {
    float xv = x[(size_t)node * K + k];
    p0 += xv * wv[k * 3 + 0];
    p1 += xv * wv[k * 3 + 1];
    p2 += xv * wv[k * 3 + 2];
  }
#pragma unroll
  for (int off = 32; off; off >>= 1) {
    p0 += __shfl_xor(p0, off);
    p1 += __shfl_xor(p1, off);
    p2 += __shfl_xor(p2, off);
  }
  if (lane == 0) {
    out[node * 3 + 0] = p0;
    out[node * 3 + 1] = p1;
    out[node * 3 + 2] = p2;
  }
}

// ------------- fill uint32 --------------------------------------------------
__global__ void fill_u32(unsigned* __restrict__ p, unsigned v, int n) {
  int i = blockIdx.x * blockDim.x + threadIdx.x;
  if (i < n) p[i] = v;
}

// ------------- edge pass 1: segment max ------------------------------------
__global__ void edge_max(const int* __restrict__ src, const int* __restrict__ dst,
                         const float* __restrict__ als, const float* __restrict__ ald,
                         unsigned* __restrict__ menc, int E) {
  int e = blockIdx.x * blockDim.x + threadIdx.x;
  if (e >= E) return;
  int s = src[e], d = dst[e];
#pragma unroll
  for (int h = 0; h < H; ++h) {
    float v = als[s * 3 + h] + ald[d * 3 + h];
    v = v > 0.f ? v : NEG * v;
    atomicMax(&menc[d * 3 + h], fenc(v));
  }
}

// ------------- edge pass 2: exp + scatter (wave per edge) ------------------
__global__ void edge_msg(const int* __restrict__ src, const int* __restrict__ dst,
                         const float* __restrict__ als, const float* __restrict__ ald,
                         const unsigned* __restrict__ menc, const float* __restrict__ hs,
                         float* __restrict__ den, float* __restrict__ outv, int E) {
  int lane = threadIdx.x & 63;
  int e = (blockIdx.x * blockDim.x + threadIdx.x) >> 6;
  if (e >= E) return;
  int s = src[e], d = dst[e];
  const float* hsrow = hs + (size_t)s * HC;
  float* orow = outv + (size_t)d * HC;
#pragma unroll
  for (int h = 0; h < H; ++h) {
    float v = als[s * 3 + h] + ald[d * 3 + h];
    v = v > 0.f ? v : NEG * v;
    float ex = expf(v - fdec(menc[d * 3 + h]));
    if (lane == h) atomicAdd(&den[d * 3 + h], ex);
    atomicAdd(&orow[h * C + lane], hsrow[h * C + lane] * ex);
  }
}

// ------------- finalize: divide, bias, relu --------------------------------
__global__ void finalize(float* __restrict__ outv, const float* __restrict__ den,
                         const float* __restrict__ b, int N) {
  int i = blockIdx.x * blockDim.x + threadIdx.x;
  if (i >= N * HC) return;
  int n = i / HC, c = i - n * HC, h = c >> 6;
  float dn = den[n * 3 + h];
  float v = (dn > 0.f) ? outv[i] / dn : 0.f;
  v += b[c];
  outv[i] = fmaxf(v, 0.f);
}

// ------------- mean-pool partial sums (sorted batch, flush on change) ------
__global__ void pool_kernel(const float* __restrict__ x, const int* __restrict__ batch,
                            float* __restrict__ pool, float* __restrict__ cnt, int N) {
  int c = threadIdx.x;  // 0..191
  int n0 = blockIdx.x * 64;
  int nend = min(n0 + 64, N);
  float acc = 0.f, cacc = 0.f;
  int cur = batch[n0];
  for (int n = n0; n < nend; ++n) {
    int bg = batch[n];
    if (bg != cur) {
      atomicAdd(&pool[(size_t)cur * HC + c], acc);
      if (c == 0) atomicAdd(&cnt[cur], cacc);
      acc = 0.f;
      cacc = 0.f;
      cur = bg;
    }
    acc += x[(size_t)n * HC + c];
    cacc += 1.f;
  }
  atomicAdd(&pool[(size_t)cur * HC + c], acc);
  if (c == 0) atomicAdd(&cnt[cur], cacc);
}

// ------------- final linear: [32,576] @ [576,2] ----------------------------
__global__ void final_linear(const float* __restrict__ pool, const float* __restrict__ cnt,
                             const float* __restrict__ linW, const float* __restrict__ linb,
                             float* __restrict__ out) {
  int tid = threadIdx.x;
  if (tid >= 64) return;
  int b = tid >> 1, o = tid & 1;
  float s = linb[o];
#pragma unroll
  for (int t = 0; t < 3; ++t) {
    float inv = 1.f / fmaxf(cnt[t * 32 + b], 1.f);
    const float* p = pool + ((size_t)t * 32 + b) * HC;
    for (int j = 0; j < HC; ++j)
      s += p[j] * inv * linW[(t * HC + j) * 2 + o];
  }
  out[b * 2 + o] = s;
}

extern "C" void kernel_launch(void* const* d_in, const int* in_sizes, int n_in,
                              void* d_out, int out_size, void* d_ws, size_t ws_size,
                              hipStream_t stream) {
  const float* xA = (const float*)d_in[0];
  const float* xT = (const float*)d_in[1];
  const float* xU = (const float*)d_in[2];
  const float* Ws1 = (const float*)d_in[3];
  const float* Wd1 = (const float*)d_in[4];
  const float* as1 = (const float*)d_in[5];
  const float* ad1 = (const float*)d_in[6];
  const float* b1 = (const float*)d_in[7];
  const float* Ws2 = (const float*)d_in[8];
  const float* Wd2 = (const float*)d_in[9];
  const float* as2 = (const float*)d_in[10];
  const float* ad2 = (const float*)d_in[11];
  const float* b2 = (const float*)d_in[12];
  const float* linW = (const float*)d_in[13];
  const float* linb = (const float*)d_in[14];
  const int* srcs[3] = {(const int*)d_in[15], (const int*)d_in[17], (const int*)d_in[19]};
  const int* dsts[3] = {(const int*)d_in[16], (const int*)d_in[18], (const int*)d_in[20]};
  const int* batA = (const int*)d_in[21];
  const int* batT = (const int*)d_in[22];
  const int* batU = (const int*)d_in[23];

  float* ws = (float*)d_ws;
  size_t off = 0;
  auto alloc = [&](size_t n) { float* p = ws + off; off += n; return p; };
  float* hs = alloc((size_t)N_T * HC);        // 19.2M
  float* als = alloc((size_t)N_T * H);
  float* ald = alloc((size_t)N_T * H);
  unsigned* menc = (unsigned*)alloc((size_t)N_T * H);
  float* den = alloc((size_t)N_T * H);
  float* x1a = alloc((size_t)N_A * HC);
  float* x1t = alloc((size_t)N_T * HC);
  float* x1u = alloc((size_t)N_U * HC);
  float* x2a = alloc((size_t)N_A * HC);
  float* x2t = alloc((size_t)N_T * HC);
  float* x2u = alloc((size_t)N_U * HC);
  float* wsv = alloc(256 * 3);
  float* wdv = alloc(256 * 3);
  float* pool = alloc(3 * 32 * HC);
  float* cnt = alloc(96);
  (void)ws_size; (void)in_sizes; (void)n_in; (void)out_size;

  const int Ecnt[3] = {E0c, E1c, E2c};
  const int NsA[3] = {N_T, N_U, N_T};
  const int NdA[3] = {N_A, N_T, N_U};

  for (int layer = 0; layer < 2; ++layer) {
    int K = layer ? HC : 256;
    const float* Wsl = layer ? Ws2 : Ws1;
    const float* Wdl = layer ? Wd2 : Wd1;
    const float* asl = layer ? as2 : as1;
    const float* adl = layer ? ad2 : ad1;
    const float* bl = layer ? b2 : b1;
    const float* xsrc[3];
    const float* xdst[3];
    float* outx[3];
    if (layer == 0) {
      xsrc[0] = xT; xsrc[1] = xU; xsrc[2] = xT;
      xdst[0] = xA; xdst[1] = xT; xdst[2] = xU;
      outx[0] = x1a; outx[1] = x1t; outx[2] = x1u;
    } else {
      xsrc[0] = x1t; xsrc[1] = x1u; xsrc[2] = x1t;
      xdst[0] = x1a; xdst[1] = x1t; xdst[2] = x1u;
      outx[0] = x2a; outx[1] = x2t; outx[2] = x2u;
    }
    for (int t = 0; t < 3; ++t) {
      int Ns = NsA[t], Nd = NdA[t], E = Ecnt[t];
      const float* Wt = Wsl + (size_t)t * K * HC;
      const float* Wdt = Wdl + (size_t)t * K * HC;
      wvec_kernel<<<1, 256, 0, stream>>>(Wt, asl + t * HC, wsv, K);
      wvec_kernel<<<1, 256, 0, stream>>>(Wdt, adl + t * HC, wdv, K);
      gemm_f32<<<dim3((Ns + BM - 1) / BM, HC / BN), 256, 0, stream>>>(xsrc[t], Wt, hs, Ns, K);
      attn_proj<<<(Ns + 3) / 4, 256, 0, stream>>>(xsrc[t], wsv, als, Ns, K);
      attn_proj<<<(Nd + 3) / 4, 256, 0, stream>>>(xdst[t], wdv, ald, Nd, K);
      fill_u32<<<(Nd * 3 + 255) / 256, 256, 0, stream>>>(menc, 0x007FFFFFu, Nd * 3);
      hipMemsetAsync(den, 0, (size_t)Nd * 3 * sizeof(float), stream);
      hipMemsetAsync(outx[t], 0, (size_t)Nd * HC * sizeof(float), stream);
      edge_max<<<(E + 255) / 256, 256, 0, stream>>>(srcs[t], dsts[t], als, ald, menc, E);
      edge_msg<<<(E + 3) / 4, 256, 0, stream>>>(srcs[t], dsts[t], als, ald, menc, hs, den, outx[t], E);
      finalize<<<((int)((size_t)Nd * HC + 255) / 256), 256, 0, stream>>>(outx[t], den, bl + t * HC, Nd);
    }
  }

  hipMemsetAsync(pool, 0, 3 * 32 * HC * sizeof(float), stream);
  hipMemsetAsync(cnt, 0, 96 * sizeof(float), stream);
  pool_kernel<<<(N_A + 63) / 64, 192, 0, stream>>>(x2a, batA, pool + 0, cnt + 0, N_A);
  pool_kernel<<<(N_T + 63) / 64, 192, 0, stream>>>(x2t, batT, pool + 32 * HC, cnt + 32, N_T);
  pool_kernel<<<(N_U + 63) / 64, 192, 0, stream>>>(x2u, batU, pool + 64 * HC, cnt + 64, N_U);
  final_linear<<<1, 64, 0, stream>>>(pool, cnt, linW, linb, (float*)d_out);
}

// Round 2
// 1724.271 us; speedup vs baseline: 1.6932x; 1.6932x over previous
//
#include <hip/hip_runtime.h>
#include <cstdint>

#define H 3
#define C 64
#define HC 192
#define NEG 0.2f

#define N_A 10000
#define N_T 100000
#define N_U 50000
#define E0c 200000
#define E1c 300000
#define E2c 300000

// ---------------- GEMM: C[N,192] = A[N,K] @ W[K,192], fp32 -----------------
#define BM 128
#define BN 64
#define BK 16

__global__ __launch_bounds__(256) void gemm_f32(
    const float* __restrict__ A, const float* __restrict__ W,
    float* __restrict__ Cmat, int N, int K) {
  __shared__ float As[BK][BM + 4];
  __shared__ float Bs[BK][BN + 4];
  const int tid = threadIdx.x;
  const int bm = blockIdx.x * BM;
  const int bn = blockIdx.y * BN;
  const int tx = tid & 15, ty = tid >> 4;
  float acc[8][4];
#pragma unroll
  for (int i = 0; i < 8; ++i)
#pragma unroll
    for (int j = 0; j < 4; ++j) acc[i][j] = 0.f;

  for (int k0 = 0; k0 < K; k0 += BK) {
#pragma unroll
    for (int i = 0; i < 2; ++i) {
      int idx = tid + i * 256;
      int m = idx >> 2, k4 = idx & 3;
      int gm = bm + m;
      float4 v = make_float4(0.f, 0.f, 0.f, 0.f);
      if (gm < N) v = *(const float4*)(A + (size_t)gm * K + k0 + k4 * 4);
      As[k4 * 4 + 0][m] = v.x;
      As[k4 * 4 + 1][m] = v.y;
      As[k4 * 4 + 2][m] = v.z;
      As[k4 * 4 + 3][m] = v.w;
    }
    {
      int k = tid >> 4, n4 = tid & 15;
      float4 v = *(const float4*)(W + (size_t)(k0 + k) * HC + bn + n4 * 4);
      *(float4*)&Bs[k][n4 * 4] = v;
    }
    __syncthreads();
#pragma unroll
    for (int k = 0; k < BK; ++k) {
      float4 a0 = *(const float4*)&As[k][ty * 8];
      float4 a1 = *(const float4*)&As[k][ty * 8 + 4];
      float4 b = *(const float4*)&Bs[k][tx * 4];
      float av[8] = {a0.x, a0.y, a0.z, a0.w, a1.x, a1.y, a1.z, a1.w};
      float bv[4] = {b.x, b.y, b.z, b.w};
#pragma unroll
      for (int i = 0; i < 8; ++i)
#pragma unroll
        for (int j = 0; j < 4; ++j) acc[i][j] += av[i] * bv[j];
    }
    __syncthreads();
  }
#pragma unroll
  for (int i = 0; i < 8; ++i) {
    int gm = bm + ty * 8 + i;
    if (gm < N) {
      float4 v = make_float4(acc[i][0], acc[i][1], acc[i][2], acc[i][3]);
      *(float4*)(Cmat + (size_t)gm * HC + bn + tx * 4) = v;
    }
  }
}

// ------------- wv[k][h] = sum_c W[k][h*64+c] * a[h*64+c] -------------------
__global__ void wvec_kernel(const float* __restrict__ W,
                            const float* __restrict__ a,
                            float* __restrict__ wv, int K) {
  int k = blockIdx.x * blockDim.x + threadIdx.x;
  if (k >= K) return;
#pragma unroll
  for (int h = 0; h < H; ++h) {
    float s = 0.f;
    for (int c = 0; c < C; ++c) s += W[(size_t)k * HC + h * C + c] * a[h * C + c];
    wv[k * H + h] = s;
  }
}

// ------------- out[n][h] = sum_k x[n][k] * wv[k][h]  (wave per node) -------
__global__ void attn_proj(const float* __restrict__ x,
                          const float* __restrict__ wv,
                          float* __restrict__ out, int N, int K) {
  int lane = threadIdx.x & 63;
  int node = (blockIdx.x * blockDim.x + threadIdx.x) >> 6;
  if (node >= N) return;
  float p0 = 0.f, p1 = 0.f, p2 = 0.f;
  for (int k = lane; k < K; k += 64) {
    float xv = x[(size_t)node * K + k];
    p0 += xv * wv[k * 3 + 0];
    p1 += xv * wv[k * 3 + 1];
    p2 += xv * wv[k * 3 + 2];
  }
#pragma unroll
  for (int off = 32; off; off >>= 1) {
    p0 += __shfl_xor(p0, off);
    p1 += __shfl_xor(p1, off);
    p2 += __shfl_xor(p2, off);
  }
  if (lane == 0) {
    out[node * 3 + 0] = p0;
    out[node * 3 + 1] = p1;
    out[node * 3 + 2] = p2;
  }
}

// ================= CSR build =================
__global__ void csr_count(const int* __restrict__ dst, int* __restrict__ pos, int E) {
  int e = blockIdx.x * blockDim.x + threadIdx.x;
  if (e < E) atomicAdd(&pos[dst[e]], 1);
}

// per-1024-chunk sums
__global__ void scan_block_sums(const int* __restrict__ deg, int* __restrict__ bsum, int n) {
  __shared__ int sdata[256];
  int base = blockIdx.x * 1024;
  int t = threadIdx.x;
  int s = 0;
  for (int i = t; i < 1024; i += 256) {
    int idx = base + i;
    s += (idx < n) ? deg[idx] : 0;
  }
  sdata[t] = s;
  __syncthreads();
  for (int o = 128; o; o >>= 1) {
    if (t < o) sdata[t] += sdata[t + o];
    __syncthreads();
  }
  if (t == 0) bsum[blockIdx.x] = sdata[0];
}

// exclusive scan of chunk sums (nb <= 1024)
__global__ void scan_bsum(int* __restrict__ bsum, int nb) {
  __shared__ int sh[1024];
  int t = threadIdx.x;
  int v = (t < nb) ? bsum[t] : 0;
  sh[t] = v;
  __syncthreads();
  for (int o = 1; o < 1024; o <<= 1) {
    int x = (t >= o) ? sh[t - o] : 0;
    __syncthreads();
    sh[t] += x;
    __syncthreads();
  }
  if (t < nb) bsum[t] = sh[t] - v;  // exclusive
}

// per-chunk exclusive scan + offset -> rowptr, pos
__global__ void scan_chunks(const int* __restrict__ deg, const int* __restrict__ bsum,
                            int* __restrict__ rowptr, int* __restrict__ pos, int n) {
  __shared__ int sh[1024];
  int t = threadIdx.x;
  int idx = blockIdx.x * 1024 + t;
  int v = (idx < n) ? deg[idx] : 0;
  sh[t] = v;
  __syncthreads();
  for (int o = 1; o < 1024; o <<= 1) {
    int x = (t >= o) ? sh[t - o] : 0;
    __syncthreads();
    sh[t] += x;
    __syncthreads();
  }
  if (idx < n) {
    int ex = sh[t] - v + bsum[blockIdx.x];
    rowptr[idx] = ex;
    pos[idx] = ex;
  }
  if (idx == n - 1) rowptr[n] = sh[t] + bsum[blockIdx.x];
}

__global__ void csr_fill(const int* __restrict__ src, const int* __restrict__ dst,
                         int* __restrict__ pos, int* __restrict__ csrc, int E) {
  int e = blockIdx.x * blockDim.x + threadIdx.x;
  if (e >= E) return;
  int slot = atomicAdd(&pos[dst[e]], 1);
  csrc[slot] = src[e];
}

// ============ fused gather: max + softmax + aggregate + bias + relu ========
__global__ __launch_bounds__(256) void gat_gather(
    const int* __restrict__ rowptr, const int* __restrict__ csrc,
    const float* __restrict__ als, const float* __restrict__ ald,
    const float* __restrict__ hs, const float* __restrict__ bias,
    float* __restrict__ outx, int Nd) {
  int lane = threadIdx.x & 63;
  int d = (blockIdx.x * 256 + threadIdx.x) >> 6;
  if (d >= Nd) return;
  int beg = rowptr[d], end = rowptr[d + 1];
  float ad0 = ald[d * 3 + 0], ad1 = ald[d * 3 + 1], ad2 = ald[d * 3 + 2];

  // pass 1: per-head max (lanes split edges, then reduce)
  float m0 = -1e30f, m1 = -1e30f, m2 = -1e30f;
  for (int j = beg + lane; j < end; j += 64) {
    int s = csrc[j];
    float l0 = als[s * 3 + 0] + ad0; l0 = l0 > 0.f ? l0 : NEG * l0;
    float l1 = als[s * 3 + 1] + ad1; l1 = l1 > 0.f ? l1 : NEG * l1;
    float l2 = als[s * 3 + 2] + ad2; l2 = l2 > 0.f ? l2 : NEG * l2;
    m0 = fmaxf(m0, l0); m1 = fmaxf(m1, l1); m2 = fmaxf(m2, l2);
  }
#pragma unroll
  for (int o = 32; o; o >>= 1) {
    m0 = fmaxf(m0, __shfl_xor(m0, o));
    m1 = fmaxf(m1, __shfl_xor(m1, o));
    m2 = fmaxf(m2, __shfl_xor(m2, o));
  }

  // pass 2: exp weights + message accumulation (lane = channel)
  float den0 = 0.f, den1 = 0.f, den2 = 0.f;
  float acc0 = 0.f, acc1 = 0.f, acc2 = 0.f;
  for (int j = beg; j < end; ++j) {
    int s = csrc[j];
    float l0 = als[s * 3 + 0] + ad0; l0 = l0 > 0.f ? l0 : NEG * l0;
    float l1 = als[s * 3 + 1] + ad1; l1 = l1 > 0.f ? l1 : NEG * l1;
    float l2 = als[s * 3 + 2] + ad2; l2 = l2 > 0.f ? l2 : NEG * l2;
    float w0 = __expf(l0 - m0);
    float w1 = __expf(l1 - m1);
    float w2 = __expf(l2 - m2);
    den0 += w0; den1 += w1; den2 += w2;
    const float* hr = hs + (size_t)s * HC;
    acc0 += w0 * hr[lane];
    acc1 += w1 * hr[64 + lane];
    acc2 += w2 * hr[128 + lane];
  }
  float i0 = den0 > 0.f ? 1.f / den0 : 0.f;
  float i1 = den1 > 0.f ? 1.f / den1 : 0.f;
  float i2 = den2 > 0.f ? 1.f / den2 : 0.f;
  float* orow = outx + (size_t)d * HC;
  orow[lane]       = fmaxf(acc0 * i0 + bias[lane], 0.f);
  orow[64 + lane]  = fmaxf(acc1 * i1 + bias[64 + lane], 0.f);
  orow[128 + lane] = fmaxf(acc2 * i2 + bias[128 + lane], 0.f);
}

// ------------- mean-pool partial sums (sorted batch, flush on change) ------
__global__ void pool_kernel(const float* __restrict__ x, const int* __restrict__ batch,
                            float* __restrict__ pool, float* __restrict__ cnt, int N) {
  int c = threadIdx.x;  // 0..191
  int n0 = blockIdx.x * 64;
  int nend = min(n0 + 64, N);
  float acc = 0.f, cacc = 0.f;
  int cur = batch[n0];
  for (int n = n0; n < nend; ++n) {
    int bg = batch[n];
    if (bg != cur) {
      atomicAdd(&pool[(size_t)cur * HC + c], acc);
      if (c == 0) atomicAdd(&cnt[cur], cacc);
      acc = 0.f;
      cacc = 0.f;
      cur = bg;
    }
    acc += x[(size_t)n * HC + c];
    cacc += 1.f;
  }
  atomicAdd(&pool[(size_t)cur * HC + c], acc);
  if (c == 0) atomicAdd(&cnt[cur], cacc);
}

// ------------- final linear: [32,576] @ [576,2] ----------------------------
__global__ void final_linear(const float* __restrict__ pool, const float* __restrict__ cnt,
                             const float* __restrict__ linW, const float* __restrict__ linb,
                             float* __restrict__ out) {
  int tid = threadIdx.x;
  if (tid >= 64) return;
  int b = tid >> 1, o = tid & 1;
  float s = linb[o];
#pragma unroll
  for (int t = 0; t < 3; ++t) {
    float inv = 1.f / fmaxf(cnt[t * 32 + b], 1.f);
    const float* p = pool + ((size_t)t * 32 + b) * HC;
    for (int j = 0; j < HC; ++j)
      s += p[j] * inv * linW[(t * HC + j) * 2 + o];
  }
  out[b * 2 + o] = s;
}

extern "C" void kernel_launch(void* const* d_in, const int* in_sizes, int n_in,
                              void* d_out, int out_size, void* d_ws, size_t ws_size,
                              hipStream_t stream) {
  const float* xA = (const float*)d_in[0];
  const float* xT = (const float*)d_in[1];
  const float* xU = (const float*)d_in[2];
  const float* Ws1 = (const float*)d_in[3];
  const float* Wd1 = (const float*)d_in[4];
  const float* as1 = (const float*)d_in[5];
  const float* ad1 = (const float*)d_in[6];
  const float* b1 = (const float*)d_in[7];
  const float* Ws2 = (const float*)d_in[8];
  const float* Wd2 = (const float*)d_in[9];
  const float* as2 = (const float*)d_in[10];
  const float* ad2 = (const float*)d_in[11];
  const float* b2 = (const float*)d_in[12];
  const float* linW = (const float*)d_in[13];
  const float* linb = (const float*)d_in[14];
  const int* srcs[3] = {(const int*)d_in[15], (const int*)d_in[17], (const int*)d_in[19]};
  const int* dsts[3] = {(const int*)d_in[16], (const int*)d_in[18], (const int*)d_in[20]};
  const int* batA = (const int*)d_in[21];
  const int* batT = (const int*)d_in[22];
  const int* batU = (const int*)d_in[23];

  float* ws = (float*)d_ws;
  size_t off = 0;
  auto alloc = [&](size_t n) { float* p = ws + off; off += n; return p; };
  float* hs = alloc((size_t)N_T * HC);
  float* als = alloc((size_t)N_T * H);
  float* ald = alloc((size_t)N_T * H);
  float* x1a = alloc((size_t)N_A * HC);
  float* x1t = alloc((size_t)N_T * HC);
  float* x1u = alloc((size_t)N_U * HC);
  float* x2a = alloc((size_t)N_A * HC);
  float* x2t = alloc((size_t)N_T * HC);
  float* x2u = alloc((size_t)N_U * HC);
  float* wsv = alloc(256 * 3);
  float* wdv = alloc(256 * 3);
  float* pool = alloc(3 * 32 * HC);
  float* cnt = alloc(96);
  // CSR buffers
  int* rowptr[3];
  int* pos[3];
  int* csrc[3];
  const int Ecnt[3] = {E0c, E1c, E2c};
  const int NdA[3] = {N_A, N_T, N_U};
  const int NsA[3] = {N_T, N_U, N_T};
  for (int t = 0; t < 3; ++t) {
    rowptr[t] = (int*)alloc(NdA[t] + 1);
    pos[t] = (int*)alloc(NdA[t]);
    csrc[t] = (int*)alloc(Ecnt[t]);
  }
  int* bsum = (int*)alloc(1024);
  (void)ws_size; (void)in_sizes; (void)n_in; (void)out_size;

  // ---- build 3 CSRs (reused by both layers) ----
  for (int t = 0; t < 3; ++t) {
    int Nd = NdA[t], E = Ecnt[t];
    int nb = (Nd + 1023) / 1024;
    hipMemsetAsync(pos[t], 0, (size_t)Nd * sizeof(int), stream);
    csr_count<<<(E + 255) / 256, 256, 0, stream>>>(dsts[t], pos[t], E);
    scan_block_sums<<<nb, 256, 0, stream>>>(pos[t], bsum, Nd);
    scan_bsum<<<1, 1024, 0, stream>>>(bsum, nb);
    scan_chunks<<<nb, 1024, 0, stream>>>(pos[t], bsum, rowptr[t], pos[t], Nd);
    csr_fill<<<(E + 255) / 256, 256, 0, stream>>>(srcs[t], dsts[t], pos[t], csrc[t], E);
  }

  for (int layer = 0; layer < 2; ++layer) {
    int K = layer ? HC : 256;
    const float* Wsl = layer ? Ws2 : Ws1;
    const float* Wdl = layer ? Wd2 : Wd1;
    const float* asl = layer ? as2 : as1;
    const float* adl = layer ? ad2 : ad1;
    const float* bl = layer ? b2 : b1;
    const float* xsrc[3];
    const float* xdst[3];
    float* outx[3];
    if (layer == 0) {
      xsrc[0] = xT; xsrc[1] = xU; xsrc[2] = xT;
      xdst[0] = xA; xdst[1] = xT; xdst[2] = xU;
      outx[0] = x1a; outx[1] = x1t; outx[2] = x1u;
    } else {
      xsrc[0] = x1t; xsrc[1] = x1u; xsrc[2] = x1t;
      xdst[0] = x1a; xdst[1] = x1t; xdst[2] = x1u;
      outx[0] = x2a; outx[1] = x2t; outx[2] = x2u;
    }
    for (int t = 0; t < 3; ++t) {
      int Ns = NsA[t], Nd = NdA[t];
      const float* Wt = Wsl + (size_t)t * K * HC;
      const float* Wdt = Wdl + (size_t)t * K * HC;
      wvec_kernel<<<1, 256, 0, stream>>>(Wt, asl + t * HC, wsv, K);
      wvec_kernel<<<1, 256, 0, stream>>>(Wdt, adl + t * HC, wdv, K);
      gemm_f32<<<dim3((Ns + BM - 1) / BM, HC / BN), 256, 0, stream>>>(xsrc[t], Wt, hs, Ns, K);
      attn_proj<<<(Ns + 3) / 4, 256, 0, stream>>>(xsrc[t], wsv, als, Ns, K);
      attn_proj<<<(Nd + 3) / 4, 256, 0, stream>>>(xdst[t], wdv, ald, Nd, K);
      gat_gather<<<(Nd + 3) / 4, 256, 0, stream>>>(rowptr[t], csrc[t], als, ald, hs,
                                                   bl + t * HC, outx[t], Nd);
    }
  }

  hipMemsetAsync(pool, 0, 3 * 32 * HC * sizeof(float), stream);
  hipMemsetAsync(cnt, 0, 96 * sizeof(float), stream);
  pool_kernel<<<(N_A + 63) / 64, 192, 0, stream>>>(x2a, batA, pool + 0, cnt + 0, N_A);
  pool_kernel<<<(N_T + 63) / 64, 192, 0, stream>>>(x2t, batT, pool + 32 * HC, cnt + 32, N_T);
  pool_kernel<<<(N_U + 63) / 64, 192, 0, stream>>>(x2u, batU, pool + 64 * HC, cnt + 64, N_U);
  final_linear<<<1, 64, 0, stream>>>(pool, cnt, linW, linb, (float*)d_out);
}

// Round 8
// 1516.454 us; speedup vs baseline: 1.9253x; 1.1370x over previous
//
#include <hip/hip_runtime.h>
#include <cstdint>

#define H 3
#define C 64
#define HC 192
#define NEG 0.2f

#define N_A 10000
#define N_T 100000
#define N_U 50000
#define E0c 200000
#define E1c 300000
#define E2c 300000

typedef __attribute__((ext_vector_type(8))) short short8;
typedef __attribute__((ext_vector_type(4))) float f32x4;

// ---------------- split fp32 -> bf16 hi + bf16 lo (RNE) --------------------
__device__ __forceinline__ void split1(float f, ushort& h, ushort& l) {
  unsigned u = __float_as_uint(f);
  unsigned r = u + 0x7FFFu + ((u >> 16) & 1u);
  h = (ushort)(r >> 16);
  float fhi = __uint_as_float((unsigned)h << 16);
  float d = f - fhi;
  unsigned u2 = __float_as_uint(d);
  unsigned r2 = u2 + 0x7FFFu + ((u2 >> 16) & 1u);
  l = (ushort)(r2 >> 16);
}
__device__ __forceinline__ void split4(float4 v, ushort4& h, ushort4& l) {
  split1(v.x, h.x, l.x);
  split1(v.y, h.y, l.y);
  split1(v.z, h.z, l.z);
  split1(v.w, h.w, l.w);
}

// ---------------- W transpose: Wt[c][k] = W[k][c] --------------------------
__global__ void wtrans_kernel(const float* __restrict__ W, float* __restrict__ Wt, int K) {
  int i = blockIdx.x * blockDim.x + threadIdx.x;
  if (i >= K * HC) return;
  int c = i / K, k = i - c * K;
  Wt[i] = W[(size_t)k * HC + c];
}

// ============ MFMA split-bf16 GEMM: C[M,192] = A[M,K] @ W[K,192] ===========
// grid.x = ceil(M/128), 256 threads (4 waves, 2x2), wave tile 64x96.
#define GBM 128
#define GBK 32
#define PAD 40

__global__ __launch_bounds__(256) void gemm_bf16x3(
    const float* __restrict__ A, const float* __restrict__ Wt,
    float* __restrict__ Cmat, int M, int K) {
  __shared__ __align__(16) ushort AsH[GBM][PAD];
  __shared__ __align__(16) ushort AsL[GBM][PAD];
  __shared__ __align__(16) ushort WsH[HC][PAD];
  __shared__ __align__(16) ushort WsL[HC][PAD];
  const int tid = threadIdx.x;
  const int lane = tid & 63;
  const int wid = tid >> 6;
  const int wr = wid >> 1;   // 0..1 : row half
  const int wc = wid & 1;    // 0..1 : col half
  const int bm = blockIdx.x * GBM;
  const int l15 = lane & 15;
  const int kgrp = lane >> 4;  // 0..3

  f32x4 acc[4][6];
#pragma unroll
  for (int i = 0; i < 4; ++i)
#pragma unroll
    for (int j = 0; j < 6; ++j) acc[i][j] = (f32x4){0.f, 0.f, 0.f, 0.f};

  for (int k0 = 0; k0 < K; k0 += GBK) {
    // ---- stage A tile 128x32 fp32 -> hi/lo bf16 (1024 float4, 4/thread)
#pragma unroll
    for (int i = 0; i < 4; ++i) {
      int fi = tid + i * 256;
      int row = fi >> 3, kq = fi & 7;
      int gm = bm + row;
      float4 v = make_float4(0.f, 0.f, 0.f, 0.f);
      if (gm < M) v = *(const float4*)(A + (size_t)gm * K + k0 + kq * 4);
      ushort4 h, l;
      split4(v, h, l);
      *(ushort4*)&AsH[row][kq * 4] = h;
      *(ushort4*)&AsL[row][kq * 4] = l;
    }
    // ---- stage W tile (transposed) 192x32 fp32 (1536 float4, 6/thread)
#pragma unroll
    for (int i = 0; i < 6; ++i) {
      int fi = tid + i * 256;
      int col = fi >> 3, kq = fi & 7;
      float4 v = *(const float4*)(Wt + (size_t)col * K + k0 + kq * 4);
      ushort4 h, l;
      split4(v, h, l);
      *(ushort4*)&WsH[col][kq * 4] = h;
      *(ushort4*)&WsL[col][kq * 4] = l;
    }
    __syncthreads();

    short8 aH[4], aL[4];
#pragma unroll
    for (int rf = 0; rf < 4; ++rf) {
      int row = wr * 64 + rf * 16 + l15;
      aH[rf] = *(const short8*)&AsH[row][kgrp * 8];
      aL[rf] = *(const short8*)&AsL[row][kgrp * 8];
    }
#pragma unroll
    for (int cf = 0; cf < 6; ++cf) {
      int col = wc * 96 + cf * 16 + l15;
      short8 bH = *(const short8*)&WsH[col][kgrp * 8];
      short8 bL = *(const short8*)&WsL[col][kgrp * 8];
#pragma unroll
      for (int rf = 0; rf < 4; ++rf) {
        acc[rf][cf] = __builtin_amdgcn_mfma_f32_16x16x32_bf16(aH[rf], bH, acc[rf][cf], 0, 0, 0);
        acc[rf][cf] = __builtin_amdgcn_mfma_f32_16x16x32_bf16(aL[rf], bH, acc[rf][cf], 0, 0, 0);
        acc[rf][cf] = __builtin_amdgcn_mfma_f32_16x16x32_bf16(aH[rf], bL, acc[rf][cf], 0, 0, 0);
      }
    }
    __syncthreads();
  }

  // ---- epilogue: D row = (lane>>4)*4 + r, col = lane&15
#pragma unroll
  for (int rf = 0; rf < 4; ++rf) {
#pragma unroll
    for (int r = 0; r < 4; ++r) {
      int row = bm + wr * 64 + rf * 16 + kgrp * 4 + r;
      if (row < M) {
#pragma unroll
        for (int cf = 0; cf < 6; ++cf) {
          Cmat[(size_t)row * HC + wc * 96 + cf * 16 + l15] = acc[rf][cf][r];
        }
      }
    }
  }
}

// ------------- wv[k][h] = sum_c W[k][h*64+c] * a[h*64+c] -------------------
__global__ void wvec_kernel(const float* __restrict__ W,
                            const float* __restrict__ a,
                            float* __restrict__ wv, int K) {
  int k = blockIdx.x * blockDim.x + threadIdx.x;
  if (k >= K) return;
#pragma unroll
  for (int h = 0; h < H; ++h) {
    float s = 0.f;
    for (int c = 0; c < C; ++c) s += W[(size_t)k * HC + h * C + c] * a[h * C + c];
    wv[k * H + h] = s;
  }
}

// ------------- out[n][h] = sum_k x[n][k] * wv[k][h]  (wave per node) -------
__global__ void attn_proj(const float* __restrict__ x,
                          const float* __restrict__ wv,
                          float* __restrict__ out, int N, int K) {
  int lane = threadIdx.x & 63;
  int node = (blockIdx.x * blockDim.x + threadIdx.x) >> 6;
  if (node >= N) return;
  float p0 = 0.f, p1 = 0.f, p2 = 0.f;
  for (int k = lane; k < K; k += 64) {
    float xv = x[(size_t)node * K + k];
    p0 += xv * wv[k * 3 + 0];
    p1 += xv * wv[k * 3 + 1];
    p2 += xv * wv[k * 3 + 2];
  }
#pragma unroll
  for (int off = 32; off; off >>= 1) {
    p0 += __shfl_xor(p0, off);
    p1 += __shfl_xor(p1, off);
    p2 += __shfl_xor(p2, off);
  }
  if (lane == 0) {
    out[node * 3 + 0] = p0;
    out[node * 3 + 1] = p1;
    out[node * 3 + 2] = p2;
  }
}

// ================= CSR build =================
__global__ void csr_count(const int* __restrict__ dst, int* __restrict__ pos, int E) {
  int e = blockIdx.x * blockDim.x + threadIdx.x;
  if (e < E) atomicAdd(&pos[dst[e]], 1);
}

__global__ void scan_block_sums(const int* __restrict__ deg, int* __restrict__ bsum, int n) {
  __shared__ int sdata[256];
  int base = blockIdx.x * 1024;
  int t = threadIdx.x;
  int s = 0;
  for (int i = t; i < 1024; i += 256) {
    int idx = base + i;
    s += (idx < n) ? deg[idx] : 0;
  }
  sdata[t] = s;
  __syncthreads();
  for (int o = 128; o; o >>= 1) {
    if (t < o) sdata[t] += sdata[t + o];
    __syncthreads();
  }
  if (t == 0) bsum[blockIdx.x] = sdata[0];
}

__global__ void scan_bsum(int* __restrict__ bsum, int nb) {
  __shared__ int sh[1024];
  int t = threadIdx.x;
  int v = (t < nb) ? bsum[t] : 0;
  sh[t] = v;
  __syncthreads();
  for (int o = 1; o < 1024; o <<= 1) {
    int x = (t >= o) ? sh[t - o] : 0;
    __syncthreads();
    sh[t] += x;
    __syncthreads();
  }
  if (t < nb) bsum[t] = sh[t] - v;  // exclusive
}

__global__ void scan_chunks(const int* __restrict__ deg, const int* __restrict__ bsum,
                            int* __restrict__ rowptr, int* __restrict__ pos, int n) {
  __shared__ int sh[1024];
  int t = threadIdx.x;
  int idx = blockIdx.x * 1024 + t;
  int v = (idx < n) ? deg[idx] : 0;
  sh[t] = v;
  __syncthreads();
  for (int o = 1; o < 1024; o <<= 1) {
    int x = (t >= o) ? sh[t - o] : 0;
    __syncthreads();
    sh[t] += x;
    __syncthreads();
  }
  if (idx < n) {
    int ex = sh[t] - v + bsum[blockIdx.x];
    rowptr[idx] = ex;
    pos[idx] = ex;
  }
  if (idx == n - 1) rowptr[n] = sh[t] + bsum[blockIdx.x];
}

__global__ void csr_fill(const int* __restrict__ src, const int* __restrict__ dst,
                         int* __restrict__ pos, int* __restrict__ csrc, int E) {
  int e = blockIdx.x * blockDim.x + threadIdx.x;
  if (e >= E) return;
  int slot = atomicAdd(&pos[dst[e]], 1);
  csrc[slot] = src[e];
}

// ============ fused gather: max + softmax + aggregate + bias + relu ========
__global__ __launch_bounds__(256) void gat_gather(
    const int* __restrict__ rowptr, const int* __restrict__ csrc,
    const float* __restrict__ als, const float* __restrict__ ald,
    const float* __restrict__ hs, const float* __restrict__ bias,
    float* __restrict__ outx, int Nd) {
  int lane = threadIdx.x & 63;
  int d = (blockIdx.x * 256 + threadIdx.x) >> 6;
  if (d >= Nd) return;
  int beg = rowptr[d], end = rowptr[d + 1];
  float ad0 = ald[d * 3 + 0], ad1 = ald[d * 3 + 1], ad2 = ald[d * 3 + 2];

  float m0 = -1e30f, m1 = -1e30f, m2 = -1e30f;
  for (int j = beg + lane; j < end; j += 64) {
    int s = csrc[j];
    float l0 = als[s * 3 + 0] + ad0; l0 = l0 > 0.f ? l0 : NEG * l0;
    float l1 = als[s * 3 + 1] + ad1; l1 = l1 > 0.f ? l1 : NEG * l1;
    float l2 = als[s * 3 + 2] + ad2; l2 = l2 > 0.f ? l2 : NEG * l2;
    m0 = fmaxf(m0, l0); m1 = fmaxf(m1, l1); m2 = fmaxf(m2, l2);
  }
#pragma unroll
  for (int o = 32; o; o >>= 1) {
    m0 = fmaxf(m0, __shfl_xor(m0, o));
    m1 = fmaxf(m1, __shfl_xor(m1, o));
    m2 = fmaxf(m2, __shfl_xor(m2, o));
  }

  float den0 = 0.f, den1 = 0.f, den2 = 0.f;
  float acc0 = 0.f, acc1 = 0.f, acc2 = 0.f;
  for (int j = beg; j < end; ++j) {
    int s = csrc[j];
    float l0 = als[s * 3 + 0] + ad0; l0 = l0 > 0.f ? l0 : NEG * l0;
    float l1 = als[s * 3 + 1] + ad1; l1 = l1 > 0.f ? l1 : NEG * l1;
    float l2 = als[s * 3 + 2] + ad2; l2 = l2 > 0.f ? l2 : NEG * l2;
    float w0 = __expf(l0 - m0);
    float w1 = __expf(l1 - m1);
    float w2 = __expf(l2 - m2);
    den0 += w0; den1 += w1; den2 += w2;
    const float* hr = hs + (size_t)s * HC;
    acc0 += w0 * hr[lane];
    acc1 += w1 * hr[64 + lane];
    acc2 += w2 * hr[128 + lane];
  }
  float i0 = den0 > 0.f ? 1.f / den0 : 0.f;
  float i1 = den1 > 0.f ? 1.f / den1 : 0.f;
  float i2 = den2 > 0.f ? 1.f / den2 : 0.f;
  float* orow = outx + (size_t)d * HC;
  orow[lane]       = fmaxf(acc0 * i0 + bias[lane], 0.f);
  orow[64 + lane]  = fmaxf(acc1 * i1 + bias[64 + lane], 0.f);
  orow[128 + lane] = fmaxf(acc2 * i2 + bias[128 + lane], 0.f);
}

// ------------- mean-pool partial sums (sorted batch, flush on change) ------
__global__ void pool_kernel(const float* __restrict__ x, const int* __restrict__ batch,
                            float* __restrict__ pool, float* __restrict__ cnt, int N) {
  int c = threadIdx.x;  // 0..191
  int n0 = blockIdx.x * 64;
  int nend = min(n0 + 64, N);
  float acc = 0.f, cacc = 0.f;
  int cur = batch[n0];
  for (int n = n0; n < nend; ++n) {
    int bg = batch[n];
    if (bg != cur) {
      atomicAdd(&pool[(size_t)cur * HC + c], acc);
      if (c == 0) atomicAdd(&cnt[cur], cacc);
      acc = 0.f;
      cacc = 0.f;
      cur = bg;
    }
    acc += x[(size_t)n * HC + c];
    cacc += 1.f;
  }
  atomicAdd(&pool[(size_t)cur * HC + c], acc);
  if (c == 0) atomicAdd(&cnt[cur], cacc);
}

// ------------- final linear: [32,576] @ [576,2] ----------------------------
__global__ void final_linear(const float* __restrict__ pool, const float* __restrict__ cnt,
                             const float* __restrict__ linW, const float* __restrict__ linb,
                             float* __restrict__ out) {
  int tid = threadIdx.x;
  if (tid >= 64) return;
  int b = tid >> 1, o = tid & 1;
  float s = linb[o];
#pragma unroll
  for (int t = 0; t < 3; ++t) {
    float inv = 1.f / fmaxf(cnt[t * 32 + b], 1.f);
    const float* p = pool + ((size_t)t * 32 + b) * HC;
    for (int j = 0; j < HC; ++j)
      s += p[j] * inv * linW[(t * HC + j) * 2 + o];
  }
  out[b * 2 + o] = s;
}

extern "C" void kernel_launch(void* const* d_in, const int* in_sizes, int n_in,
                              void* d_out, int out_size, void* d_ws, size_t ws_size,
                              hipStream_t stream) {
  const float* xA = (const float*)d_in[0];
  const float* xT = (const float*)d_in[1];
  const float* xU = (const float*)d_in[2];
  const float* Ws1 = (const float*)d_in[3];
  const float* Wd1 = (const float*)d_in[4];
  const float* as1 = (const float*)d_in[5];
  const float* ad1 = (const float*)d_in[6];
  const float* b1 = (const float*)d_in[7];
  const float* Ws2 = (const float*)d_in[8];
  const float* Wd2 = (const float*)d_in[9];
  const float* as2 = (const float*)d_in[10];
  const float* ad2 = (const float*)d_in[11];
  const float* b2 = (const float*)d_in[12];
  const float* linW = (const float*)d_in[13];
  const float* linb = (const float*)d_in[14];
  const int* srcs[3] = {(const int*)d_in[15], (const int*)d_in[17], (const int*)d_in[19]};
  const int* dsts[3] = {(const int*)d_in[16], (const int*)d_in[18], (const int*)d_in[20]};
  const int* batA = (const int*)d_in[21];
  const int* batT = (const int*)d_in[22];
  const int* batU = (const int*)d_in[23];

  float* ws = (float*)d_ws;
  size_t off = 0;
  auto alloc = [&](size_t n) { float* p = ws + off; off += n; return p; };
  float* hs = alloc((size_t)N_T * HC);
  float* als = alloc((size_t)N_T * H);
  float* ald = alloc((size_t)N_T * H);
  float* x1a = alloc((size_t)N_A * HC);
  float* x1t = alloc((size_t)N_T * HC);
  float* x1u = alloc((size_t)N_U * HC);
  float* x2a = alloc((size_t)N_A * HC);
  float* x2t = alloc((size_t)N_T * HC);
  float* x2u = alloc((size_t)N_U * HC);
  float* wsv = alloc(256 * 3);
  float* wdv = alloc(256 * 3);
  float* pool = alloc(3 * 32 * HC);
  float* cnt = alloc(96);
  float* wt = alloc((size_t)HC * 256);  // transposed weight scratch
  // CSR buffers
  int* rowptr[3];
  int* pos[3];
  int* csrc[3];
  const int Ecnt[3] = {E0c, E1c, E2c};
  const int NdA[3] = {N_A, N_T, N_U};
  const int NsA[3] = {N_T, N_U, N_T};
  for (int t = 0; t < 3; ++t) {
    rowptr[t] = (int*)alloc(NdA[t] + 1);
    pos[t] = (int*)alloc(NdA[t]);
    csrc[t] = (int*)alloc(Ecnt[t]);
  }
  int* bsum = (int*)alloc(1024);
  (void)ws_size; (void)in_sizes; (void)n_in; (void)out_size;

  // ---- build 3 CSRs (reused by both layers) ----
  for (int t = 0; t < 3; ++t) {
    int Nd = NdA[t], E = Ecnt[t];
    int nb = (Nd + 1023) / 1024;
    hipMemsetAsync(pos[t], 0, (size_t)Nd * sizeof(int), stream);
    csr_count<<<(E + 255) / 256, 256, 0, stream>>>(dsts[t], pos[t], E);
    scan_block_sums<<<nb, 256, 0, stream>>>(pos[t], bsum, Nd);
    scan_bsum<<<1, 1024, 0, stream>>>(bsum, nb);
    scan_chunks<<<nb, 1024, 0, stream>>>(pos[t], bsum, rowptr[t], pos[t], Nd);
    csr_fill<<<(E + 255) / 256, 256, 0, stream>>>(srcs[t], dsts[t], pos[t], csrc[t], E);
  }

  for (int layer = 0; layer < 2; ++layer) {
    int K = layer ? HC : 256;
    const float* Wsl = layer ? Ws2 : Ws1;
    const float* Wdl = layer ? Wd2 : Wd1;
    const float* asl = layer ? as2 : as1;
    const float* adl = layer ? ad2 : ad1;
    const float* bl = layer ? b2 : b1;
    const float* xsrc[3];
    const float* xdst[3];
    float* outx[3];
    if (layer == 0) {
      xsrc[0] = xT; xsrc[1] = xU; xsrc[2] = xT;
      xdst[0] = xA; xdst[1] = xT; xdst[2] = xU;
      outx[0] = x1a; outx[1] = x1t; outx[2] = x1u;
    } else {
      xsrc[0] = x1t; xsrc[1] = x1u; xsrc[2] = x1t;
      xdst[0] = x1a; xdst[1] = x1t; xdst[2] = x1u;
      outx[0] = x2a; outx[1] = x2t; outx[2] = x2u;
    }
    for (int t = 0; t < 3; ++t) {
      int Ns = NsA[t], Nd = NdA[t];
      const float* Wt = Wsl + (size_t)t * K * HC;
      const float* Wdt = Wdl + (size_t)t * K * HC;
      wvec_kernel<<<1, 256, 0, stream>>>(Wt, asl + t * HC, wsv, K);
      wvec_kernel<<<1, 256, 0, stream>>>(Wdt, adl + t * HC, wdv, K);
      wtrans_kernel<<<(K * HC + 255) / 256, 256, 0, stream>>>(Wt, wt, K);
      gemm_bf16x3<<<(Ns + GBM - 1) / GBM, 256, 0, stream>>>(xsrc[t], wt, hs, Ns, K);
      attn_proj<<<(Ns + 3) / 4, 256, 0, stream>>>(xsrc[t], wsv, als, Ns, K);
      attn_proj<<<(Nd + 3) / 4, 256, 0, stream>>>(xdst[t], wdv, ald, Nd, K);
      gat_gather<<<(Nd + 3) / 4, 256, 0, stream>>>(rowptr[t], csrc[t], als, ald, hs,
                                                   bl + t * HC, outx[t], Nd);
    }
  }

  hipMemsetAsync(pool, 0, 3 * 32 * HC * sizeof(float), stream);
  hipMemsetAsync(cnt, 0, 96 * sizeof(float), stream);
  pool_kernel<<<(N_A + 63) / 64, 192, 0, stream>>>(x2a, batA, pool + 0, cnt + 0, N_A);
  pool_kernel<<<(N_T + 63) / 64, 192, 0, stream>>>(x2t, batT, pool + 32 * HC, cnt + 32, N_T);
  pool_kernel<<<(N_U + 63) / 64, 192, 0, stream>>>(x2u, batU, pool + 64 * HC, cnt + 64, N_U);
  final_linear<<<1, 64, 0, stream>>>(pool, cnt, linW, linb, (float*)d_out);
}